// Round 11
// baseline (284.662 us; speedup 1.0000x reference)
//
#include <hip/hip_runtime.h>
#include <hip/hip_bf16.h>

#define D 128

typedef __attribute__((ext_vector_type(8))) short bf16x8;
typedef __attribute__((ext_vector_type(4))) float f32x4;

__device__ __forceinline__ unsigned short f2bf_bits(float f) {
    union { __hip_bfloat16 h; unsigned short u; } c;
    c.h = __float2bfloat16(f);
    return c.u;
}
__device__ __forceinline__ float bfbits2f(unsigned short u) {
    return __uint_as_float(((unsigned)u) << 16);
}
__device__ __forceinline__ float ldf(const void* p, size_t i, int f32) {
    return f32 ? ((const float*)p)[i] : bfbits2f(((const unsigned short*)p)[i]);
}
__device__ __forceinline__ void unpk(unsigned u, float& a, float& b) {
    a = __uint_as_float(u << 16);
    b = __uint_as_float(u & 0xFFFF0000u);
}

// ---- K1: prep = dtype-detect (per-block local) + wq (transposed write)
//         + trans of 5 raw weights + count.
// wT job map: 0 Wsq_s 1 W_s 2 Wsq_d 3 W_d 4 loopW 5 evoW 6 Wsq_r 7 W_r
__global__ __launch_bounds__(256) void prep_kernel(
    const void* __restrict__ node, const void* __restrict__ wtrip,
    const void* __restrict__ wquad, const void* __restrict__ loopW,
    const void* __restrict__ evoW, unsigned short* __restrict__ wT,
    int* __restrict__ cnt, const int* __restrict__ dst, int* __restrict__ flag,
    int E) {
    __shared__ int sflag;
    int tid = threadIdx.x;
    int bad = 0;
    if (tid < 64) {
        for (int j = 0; j < 4; j++) {
            float v = bfbits2f(((const unsigned short*)node)[tid + 64 * j]);
            if (!(fabsf(v) < 1e4f)) bad = 1;
        }
    }
    unsigned long long m = __ballot(bad);
    if (tid == 0) sflag = (m != 0ull) ? 1 : 0;
    __syncthreads();
    int f32 = sflag;
    int bx = blockIdx.x;
    if (bx == 0 && tid == 0) *flag = f32;

    if (bx < 192) {
        int unit = bx * 2 + (tid >> 7);
        int k = unit & 127, mjob = unit >> 7;
        int t = tid & 127;
        float acc = 0.f;
        for (int j = 0; j < D; j++)
            acc += ldf(wtrip, (size_t)mjob * D * D + (size_t)k * D + j, f32) *
                   ldf(wquad, (size_t)j * D + t, f32);
        const int jmap0 = (mjob == 0) ? 0 : (mjob == 1 ? 6 : 2);
        wT[(size_t)jmap0 * D * D + (size_t)t * D + k] = f2bf_bits(acc);
    } else if (bx < 272) {
        int u = bx - 192;   // [0,80): 5 jobs x 16 segments
        int jr = u >> 4, seg = u & 15;
        const void* srcp; size_t base; int j;
        switch (jr) {
            case 0: srcp = wtrip; base = 0;             j = 1; break;
            case 1: srcp = wtrip; base = 2 * D * D;     j = 3; break;
            case 2: srcp = loopW; base = 0;             j = 4; break;
            case 3: srcp = evoW;  base = 0;             j = 5; break;
            default: srcp = wtrip; base = (size_t)D * D; j = 7; break;
        }
        for (int c = tid; c < 1024; c += 256) {
            int idx = seg * 1024 + c;
            int n = idx >> 7, k = idx & 127;
            unsigned short b = f32 ? f2bf_bits(((const float*)srcp)[base + (size_t)k * D + n])
                                   : ((const unsigned short*)srcp)[base + (size_t)k * D + n];
            wT[(size_t)j * D * D + (size_t)n * D + k] = b;
        }
    } else {
        int e = (bx - 272) * 256 + tid;
        if (e < E) atomicAdd(&cnt[dst[e]], 1);
    }
}

// ---- K2: per-block exclusive scan, block totals to part ----
__global__ void scan_block(const int* __restrict__ cnt, int* __restrict__ offs,
                           int* __restrict__ part, int N) {
    __shared__ int sh[256];
    int tid = threadIdx.x;
    int i = blockIdx.x * 256 + tid;
    int v = (i < N) ? cnt[i] : 0;
    sh[tid] = v;
    __syncthreads();
    for (int o = 1; o < 256; o <<= 1) {
        int t = (tid >= o) ? sh[tid - o] : 0;
        __syncthreads();
        sh[tid] += t;
        __syncthreads();
    }
    if (i < N) offs[i] = sh[tid] - v;
    if (tid == 255) part[blockIdx.x] = sh[255];
}

// ---- K3: carry fix; also seeds cur = offs for the single-atomic scatter ----
__global__ void scan_fix(int* __restrict__ offs, const int* __restrict__ part,
                         int* __restrict__ cur, int N, int E) {
    __shared__ int sh[256];
    int tid = threadIdx.x, b = blockIdx.x;
    sh[tid] = (tid < b) ? part[tid] : 0;
    __syncthreads();
    for (int o = 128; o; o >>= 1) {
        if (tid < o) sh[tid] += sh[tid + o];
        __syncthreads();
    }
    int carry = sh[0];
    int i = b * 256 + tid;
    if (i < N) {
        int v = offs[i] + carry;
        offs[i] = v;
        cur[i] = v;
    }
    if (b == 0 && tid == 0) offs[N] = E;
}

// ---- K4: persistent table GEMM + grid-stride scatter (y==3 overflow).
// Per block: stage Q -> loop row-tiles (A prefetched, no barriers) ->
// stage T -> loop again. pass0 writes even table words (Q), pass1 odd (T);
// loopSel: pass0 stores deg>0 rows (loopW), pass1 deg==0 (evoW).
__global__ __launch_bounds__(256) void gemm_kernel(
    const void* __restrict__ node, const void* __restrict__ rel,
    const unsigned short* __restrict__ wT, const int* __restrict__ cnt,
    unsigned* __restrict__ nodeST, unsigned* __restrict__ nodeDT,
    unsigned* __restrict__ relRT, unsigned* __restrict__ loopSel,
    const int* __restrict__ flag, int N, int R,
    const int* __restrict__ src, const int* __restrict__ dst,
    const int* __restrict__ et, int* __restrict__ cur,
    unsigned* __restrict__ ePack, int E) {
    __shared__ __align__(16) unsigned short Wt[D][D + 8];

    int bx = blockIdx.x, by = blockIdx.y;
    int tid = threadIdx.y * 64 + threadIdx.x;
    int relTiles = (R + 63) / 64;

    int jp, rows;
    const void* A;
    if (by == 3) {
        if (bx >= relTiles) {
            int stride = ((int)gridDim.x - relTiles) * 256;
            for (int e = (bx - relTiles) * 256 + tid; e < E; e += stride) {
                int d = dst[e];
                int pos = atomicAdd(&cur[d], 1);
                ePack[pos] = (unsigned)src[e] | ((unsigned)et[e] << 20);
            }
            return;
        }
        jp = 3; rows = R; A = rel;
    } else {
        jp = by; rows = N; A = node;
        if (bx * 64 >= rows) return;
    }

    int f32 = *flag;
    int lane = threadIdx.x, wv = threadIdx.y;
    int l16 = lane & 15, quad = lane >> 4;
    int odd = l16 & 1;
    int nTiles = (rows + 63) / 64;
    int P = (int)gridDim.x;

    int qIdx, tIdx;
    unsigned* O = nullptr;
    switch (jp) {
        case 0: qIdx = 0; tIdx = 1; O = nodeST; break;
        case 1: qIdx = 2; tIdx = 3; O = nodeDT; break;
        case 2: qIdx = 4; tIdx = 5; break;  // loopW / evoW
        default: qIdx = 6; tIdx = 7; O = relRT; break;
    }

    for (int pass = 0; pass < 2; pass++) {
        const unsigned short* g = wT + (size_t)(pass ? tIdx : qIdx) * D * D;
#pragma unroll
        for (int i = 0; i < 8; i++) {
            int c = tid + i * 256;
            *(bf16x8*)(&Wt[c >> 4][(c & 15) * 8]) =
                *(const bf16x8*)(g + (c >> 4) * 128 + (c & 15) * 8);
        }
        __syncthreads();

        int tile = bx;
        bf16x8 af[4];
        {
            int arr = tile * 64 + wv * 16 + l16;
            int arc = arr < rows ? arr : rows - 1;
            if (f32) {
                const float* Af = (const float*)A + (size_t)arc * D;
#pragma unroll
                for (int kk = 0; kk < 4; kk++)
#pragma unroll
                    for (int j = 0; j < 8; j++)
                        af[kk][j] = (short)f2bf_bits(Af[kk * 32 + quad * 8 + j]);
            } else {
#pragma unroll
                for (int kk = 0; kk < 4; kk++)
                    af[kk] = *(const bf16x8*)((const unsigned short*)A +
                                              (size_t)arc * D + kk * 32 + quad * 8);
            }
        }

        while (tile < nTiles) {
            int nxt = tile + P;
            bf16x8 afN[4];
            if (nxt < nTiles) {
                int arr = nxt * 64 + wv * 16 + l16;
                int arc = arr < rows ? arr : rows - 1;
                if (f32) {
                    const float* Af = (const float*)A + (size_t)arc * D;
#pragma unroll
                    for (int kk = 0; kk < 4; kk++)
#pragma unroll
                        for (int j = 0; j < 8; j++)
                            afN[kk][j] = (short)f2bf_bits(Af[kk * 32 + quad * 8 + j]);
                } else {
#pragma unroll
                    for (int kk = 0; kk < 4; kk++)
                        afN[kk] = *(const bf16x8*)((const unsigned short*)A +
                                                   (size_t)arc * D + kk * 32 + quad * 8);
                }
            }

            f32x4 acc[8];
#pragma unroll
            for (int i = 0; i < 8; i++) acc[i] = (f32x4){0.f, 0.f, 0.f, 0.f};
#pragma unroll
            for (int kk = 0; kk < 4; kk++) {
#pragma unroll
                for (int nt = 0; nt < 8; nt++) {
                    bf16x8 bfr = *(const bf16x8*)(&Wt[nt * 16 + l16][kk * 32 + quad * 8]);
                    acc[nt] = __builtin_amdgcn_mfma_f32_16x16x32_bf16(af[kk], bfr, acc[nt], 0, 0, 0);
                }
            }

            int cr0 = tile * 64 + wv * 16 + quad * 4;
            if (jp != 2) {
#pragma unroll
                for (int r = 0; r < 4; r++) {
                    int cr = cr0 + r;
#pragma unroll
                    for (int nt = 0; nt < 8; nt++) {
                        float v = acc[nt][r];
                        float o = __shfl_xor(v, 1);  // unconditional: all lanes
                        if (!odd && cr < rows) {
                            unsigned w = (unsigned)f2bf_bits(v) | ((unsigned)f2bf_bits(o) << 16);
                            int cn = nt * 16 + l16;  // even
                            O[(size_t)cr * 128 + cn + pass] = w;
                        }
                    }
                }
            } else {
#pragma unroll
                for (int r = 0; r < 4; r++) {
                    int cr = cr0 + r;
                    int deg = (cr < rows) ? cnt[cr] : 0;
                    int doit = (cr < rows) && (pass == 0 ? (deg > 0) : (deg == 0));
#pragma unroll
                    for (int nt = 0; nt < 8; nt++) {
                        float v = acc[nt][r];
                        float o = __shfl_xor(v, 1);
                        if (!odd && doit) {
                            unsigned w = (unsigned)f2bf_bits(v) | ((unsigned)f2bf_bits(o) << 16);
                            loopSel[(size_t)cr * 64 + nt * 8 + (l16 >> 1)] = w;
                        }
                    }
                }
            }

            if (nxt < nTiles) {
#pragma unroll
                for (int kk = 0; kk < 4; kk++) af[kk] = afN[kk];
            }
            tile = nxt;
        }
        __syncthreads();  // all Wt reads done before restage
    }
}

// ---- K5: wave-per-node aggregation + layernorm.
// Edge indices are wave-uniform -> direct broadcast loads (no ds_bpermute);
// 8 gathers of a 4-edge group issued before any math.
__global__ __launch_bounds__(256) void agg_kernel(
    const int* __restrict__ offs, const unsigned* __restrict__ ePack,
    const uint2* __restrict__ ST, const uint2* __restrict__ RT,
    const uint2* __restrict__ DT, const unsigned* __restrict__ loopSel,
    const void* __restrict__ normv, void* __restrict__ out,
    const int* __restrict__ flag, int N) {
    int n = blockIdx.x * 4 + threadIdx.y;
    if (n >= N) return;
    int f32 = *flag;
    int lane = threadIdx.x;
    int start = offs[n], end = offs[n + 1];
    int deg = end - start;

    unsigned ul = loopSel[(size_t)n * 64 + lane];
    uint2 ud = DT[(size_t)n * 64 + lane];
    float qd0, qd1, td0, td1, acc0, acc1;
    unpk(ud.x, qd0, qd1);
    unpk(ud.y, td0, td1);
    unpk(ul, acc0, acc1);

    float den0 = 0.f, den1 = 0.f, h0 = 0.f, h1 = 0.f;
#define GATH(PK, US, UR)                                              \
    uint2 US = ST[(size_t)((PK) & 0xFFFFFu) * 64 + lane];             \
    uint2 UR = RT[(size_t)((PK) >> 20) * 64 + lane];
#define EMATH(US, UR)                                                 \
    {                                                                 \
        float qs0, qs1, qr0, qr1, ts0, ts1, tr0, tr1;                 \
        unpk(US.x, qs0, qs1); unpk(UR.x, qr0, qr1);                   \
        unpk(US.y, ts0, ts1); unpk(UR.y, tr0, tr1);                   \
        float q0 = qs0 + qr0 + qd0, q1 = qs1 + qr1 + qd1;             \
        float a0 = q0 > 0.f ? q0 : 0.01f * q0;                        \
        float a1 = q1 > 0.f ? q1 : 0.01f * q1;                        \
        float ex0 = __expf(a0), ex1 = __expf(a1);                     \
        den0 += ex0; den1 += ex1;                                     \
        h0 += ex0 * (ts0 + tr0 + td0);                                \
        h1 += ex1 * (ts1 + tr1 + td1);                                \
    }
    int e = start;
    for (; e + 3 < end; e += 4) {
        unsigned p0 = ePack[e], p1 = ePack[e + 1], p2 = ePack[e + 2], p3 = ePack[e + 3];
        GATH(p0, sA, rA)
        GATH(p1, sB, rB)
        GATH(p2, sC, rC)
        GATH(p3, sD, rD)
        EMATH(sA, rA)
        EMATH(sB, rB)
        EMATH(sC, rC)
        EMATH(sD, rD)
    }
    for (; e < end; e++) {
        unsigned pp = ePack[e];
        GATH(pp, sE, rE)
        EMATH(sE, rE)
    }

    float x0, x1;
    if (deg > 0) {
        float nrm = ldf(normv, n, f32);
        x0 = h0 / den0 * nrm + acc0;
        x1 = h1 / den1 * nrm + acc1;
    } else {
        x0 = acc0;
        x1 = acc1;
    }

    float s = x0 + x1, ss = x0 * x0 + x1 * x1;
#pragma unroll
    for (int o = 32; o; o >>= 1) {
        s += __shfl_xor(s, o);
        ss += __shfl_xor(ss, o);
    }
    float mu = s * (1.f / 128.f);
    float var = ss * (1.f / 128.f) - mu * mu;
    float rstd = rsqrtf(var + 1e-5f);
    float y0 = (x0 - mu) * rstd, y1 = (x1 - mu) * rstd;

    if (f32) {
        ((float2*)out)[(size_t)n * 64 + lane] = make_float2(y0, y1);
    } else {
        unsigned ob = (unsigned)f2bf_bits(y0) | ((unsigned)f2bf_bits(y1) << 16);
        ((unsigned*)out)[(size_t)n * 64 + lane] = ob;
    }
}

extern "C" void kernel_launch(void* const* d_in, const int* in_sizes, int n_in,
                              void* d_out, int out_size, void* d_ws, size_t ws_size,
                              hipStream_t stream) {
    const void* node = d_in[0];
    const void* rel = d_in[1];
    const void* normv = d_in[2];
    const void* wtrip = d_in[3];
    const void* wquad = d_in[4];
    const void* loopW = d_in[5];
    const void* evoW = d_in[6];
    const int* src = (const int*)d_in[7];
    const int* dst = (const int*)d_in[8];
    const int* et = (const int*)d_in[9];

    int N = in_sizes[0] / D;
    int R = in_sizes[1] / D;
    int E = in_sizes[7];
    int nb = (N + 255) / 256;
    int scatBlocks = (E + 255) / 256;

    char* p = (char*)d_ws;
    auto alloc = [&](size_t bytes) -> void* {
        void* r = (void*)p;
        p += (bytes + 255) & ~(size_t)255;
        return r;
    };
    unsigned* nodeST = (unsigned*)alloc((size_t)N * 128 * 4);
    unsigned* nodeDT = (unsigned*)alloc((size_t)N * 128 * 4);
    unsigned* relRT = (unsigned*)alloc((size_t)R * 128 * 4);
    unsigned* loopSel = (unsigned*)alloc((size_t)N * 64 * 4);
    unsigned short* wT = (unsigned short*)alloc((size_t)8 * D * D * 2);
    int* cnt = (int*)alloc((size_t)N * 4);
    int* cur = (int*)alloc((size_t)N * 4);
    int* offs = (int*)alloc((size_t)(N + 1) * 4);
    int* part = (int*)alloc((size_t)(nb + 1) * 4);
    unsigned* ePack = (unsigned*)alloc((size_t)E * 4);
    int* flag = (int*)alloc(4);

    hipMemsetAsync(cnt, 0, (size_t)N * 4, stream);
    prep_kernel<<<272 + scatBlocks, 256, 0, stream>>>(
        node, wtrip, wquad, loopW, evoW, wT, cnt, dst, flag, E);
    scan_block<<<nb, 256, 0, stream>>>(cnt, offs, part, N);
    scan_fix<<<nb, 256, 0, stream>>>(offs, part, cur, N, E);
    gemm_kernel<<<dim3(256, 4), dim3(64, 4), 0, stream>>>(
        node, rel, wT, cnt, nodeST, nodeDT, relRT, loopSel, flag, N, R,
        src, dst, et, cur, ePack, E);
    agg_kernel<<<(N + 3) / 4, dim3(64, 4), 0, stream>>>(
        offs, ePack, (const uint2*)nodeST, (const uint2*)relRT, (const uint2*)nodeDT,
        loopSel, normv, d_out, flag, N);
}

// Round 12
// 281.915 us; speedup vs baseline: 1.0097x; 1.0097x over previous
//
#include <hip/hip_runtime.h>
#include <hip/hip_bf16.h>

#define D 128

typedef __attribute__((ext_vector_type(8))) short bf16x8;
typedef __attribute__((ext_vector_type(4))) float f32x4;

__device__ __forceinline__ unsigned short f2bf_bits(float f) {
    union { __hip_bfloat16 h; unsigned short u; } c;
    c.h = __float2bfloat16(f);
    return c.u;
}
__device__ __forceinline__ float bfbits2f(unsigned short u) {
    return __uint_as_float(((unsigned)u) << 16);
}
__device__ __forceinline__ float ldf(const void* p, size_t i, int f32) {
    return f32 ? ((const float*)p)[i] : bfbits2f(((const unsigned short*)p)[i]);
}
__device__ __forceinline__ void unpk(unsigned u, float& a, float& b) {
    a = __uint_as_float(u << 16);
    b = __uint_as_float(u & 0xFFFF0000u);
}

// ---- K1: prep = dtype-detect (per-block local) + wq (transposed write)
//         + trans of 5 raw weights + count.
// wT job map: 0 Wsq_s 1 W_s 2 Wsq_d 3 W_d 4 loopW 5 evoW 6 Wsq_r 7 W_r
__global__ __launch_bounds__(256) void prep_kernel(
    const void* __restrict__ node, const void* __restrict__ wtrip,
    const void* __restrict__ wquad, const void* __restrict__ loopW,
    const void* __restrict__ evoW, unsigned short* __restrict__ wT,
    int* __restrict__ cnt, const int* __restrict__ dst, int* __restrict__ flag,
    int E) {
    __shared__ int sflag;
    int tid = threadIdx.x;
    int bad = 0;
    if (tid < 64) {
        for (int j = 0; j < 4; j++) {
            float v = bfbits2f(((const unsigned short*)node)[tid + 64 * j]);
            if (!(fabsf(v) < 1e4f)) bad = 1;
        }
    }
    unsigned long long m = __ballot(bad);
    if (tid == 0) sflag = (m != 0ull) ? 1 : 0;
    __syncthreads();
    int f32 = sflag;
    int bx = blockIdx.x;
    if (bx == 0 && tid == 0) *flag = f32;

    if (bx < 192) {
        int unit = bx * 2 + (tid >> 7);
        int k = unit & 127, mjob = unit >> 7;
        int t = tid & 127;
        float acc = 0.f;
        for (int j = 0; j < D; j++)
            acc += ldf(wtrip, (size_t)mjob * D * D + (size_t)k * D + j, f32) *
                   ldf(wquad, (size_t)j * D + t, f32);
        const int jmap0 = (mjob == 0) ? 0 : (mjob == 1 ? 6 : 2);
        wT[(size_t)jmap0 * D * D + (size_t)t * D + k] = f2bf_bits(acc);
    } else if (bx < 272) {
        int u = bx - 192;   // [0,80): 5 jobs x 16 segments
        int jr = u >> 4, seg = u & 15;
        const void* srcp; size_t base; int j;
        switch (jr) {
            case 0: srcp = wtrip; base = 0;             j = 1; break;
            case 1: srcp = wtrip; base = 2 * D * D;     j = 3; break;
            case 2: srcp = loopW; base = 0;             j = 4; break;
            case 3: srcp = evoW;  base = 0;             j = 5; break;
            default: srcp = wtrip; base = (size_t)D * D; j = 7; break;
        }
        for (int c = tid; c < 1024; c += 256) {
            int idx = seg * 1024 + c;
            int n = idx >> 7, k = idx & 127;
            unsigned short b = f32 ? f2bf_bits(((const float*)srcp)[base + (size_t)k * D + n])
                                   : ((const unsigned short*)srcp)[base + (size_t)k * D + n];
            wT[(size_t)j * D * D + (size_t)n * D + k] = b;
        }
    } else {
        int e = (bx - 272) * 256 + tid;
        if (e < E) atomicAdd(&cnt[dst[e]], 1);
    }
}

// ---- K2: per-block exclusive scan, block totals to part ----
__global__ void scan_block(const int* __restrict__ cnt, int* __restrict__ offs,
                           int* __restrict__ part, int N) {
    __shared__ int sh[256];
    int tid = threadIdx.x;
    int i = blockIdx.x * 256 + tid;
    int v = (i < N) ? cnt[i] : 0;
    sh[tid] = v;
    __syncthreads();
    for (int o = 1; o < 256; o <<= 1) {
        int t = (tid >= o) ? sh[tid - o] : 0;
        __syncthreads();
        sh[tid] += t;
        __syncthreads();
    }
    if (i < N) offs[i] = sh[tid] - v;
    if (tid == 255) part[blockIdx.x] = sh[255];
}

// ---- K3: carry fix; seeds cur = offs for single-atomic scatter ----
__global__ void scan_fix(int* __restrict__ offs, const int* __restrict__ part,
                         int* __restrict__ cur, int N, int E) {
    __shared__ int sh[256];
    int tid = threadIdx.x, b = blockIdx.x;
    sh[tid] = (tid < b) ? part[tid] : 0;
    __syncthreads();
    for (int o = 128; o; o >>= 1) {
        if (tid < o) sh[tid] += sh[tid + o];
        __syncthreads();
    }
    int carry = sh[0];
    int i = b * 256 + tid;
    if (i < N) {
        int v = offs[i] + carry;
        offs[i] = v;
        cur[i] = v;
    }
    if (b == 0 && tid == 0) offs[N] = E;
}

// ---- K4: table GEMM (R10-proven per-tile pipeline: T-weights register-
// prefetched during Q-MFMA) + scatter fused at y==1 x-overflow (single atomic).
__global__ __launch_bounds__(256) void gemm_kernel(
    const void* __restrict__ node, const void* __restrict__ rel,
    const unsigned short* __restrict__ wT, const int* __restrict__ cnt,
    unsigned* __restrict__ nodeST, unsigned* __restrict__ nodeDT,
    unsigned* __restrict__ relRT, unsigned* __restrict__ loopSel,
    const int* __restrict__ flag, int N, int R, int nodeBlocks,
    const int* __restrict__ src, const int* __restrict__ dst,
    const int* __restrict__ et, int* __restrict__ cur,
    unsigned* __restrict__ ePack, int E) {
    __shared__ __align__(16) unsigned short Wt[D][D + 8];

    int bx = blockIdx.x, by = blockIdx.y;
    int tid = threadIdx.y * 64 + threadIdx.x;
    int isRel = 0, jp;
    if (bx >= nodeBlocks) {
        if (by == 1) {  // scatter range (cur pre-seeded with offs)
            int e = (bx - nodeBlocks) * 256 + tid;
            if (e < E) {
                int pos = atomicAdd(&cur[dst[e]], 1);
                ePack[pos] = (unsigned)src[e] | ((unsigned)et[e] << 20);
            }
            return;
        }
        if (by != 0 || bx - nodeBlocks >= (R + 63) / 64) return;
        isRel = 1;
        jp = 3;
    } else {
        jp = by;
    }

    int f32 = *flag;
    int rows = isRel ? R : N;
    int row0 = (isRel ? bx - nodeBlocks : bx) * 64;
    const void* A = isRel ? rel : node;

    int lane = threadIdx.x, wv = threadIdx.y;
    int l16 = lane & 15, quad = lane >> 4;
    int ar = row0 + wv * 16 + l16;
    int ar_c = ar < rows ? ar : rows - 1;

    int qIdx, tIdx;
    unsigned* O = nullptr;
    switch (jp) {
        case 0: qIdx = 0; tIdx = 1; O = nodeST; break;
        case 1: qIdx = 2; tIdx = 3; O = nodeDT; break;
        case 2: qIdx = 4; tIdx = 5; break;  // loopW/evoW pair
        default: qIdx = 6; tIdx = 7; O = relRT; break;
    }

    bf16x8 af[4];
#pragma unroll
    for (int kk = 0; kk < 4; kk++) {
        int k = kk * 32 + quad * 8;
        if (f32) {
            const float* Af = (const float*)A + (size_t)ar_c * D + k;
#pragma unroll
            for (int j = 0; j < 8; j++) af[kk][j] = (short)f2bf_bits(Af[j]);
        } else {
            af[kk] = *(const bf16x8*)((const unsigned short*)A + (size_t)ar_c * D + k);
        }
    }

    const unsigned short* gQ = wT + (size_t)qIdx * D * D;
    const unsigned short* gT = wT + (size_t)tIdx * D * D;

    bf16x8 wreg[8], wreg2[8];
#pragma unroll
    for (int i = 0; i < 8; i++) {
        int c = tid + i * 256;
        wreg[i] = *(const bf16x8*)(gQ + (c >> 4) * 128 + (c & 15) * 8);
    }

    f32x4 accQ[8], accT[8];
#pragma unroll
    for (int i = 0; i < 8; i++) {
        accQ[i] = (f32x4){0.f, 0.f, 0.f, 0.f};
        accT[i] = (f32x4){0.f, 0.f, 0.f, 0.f};
    }

    for (int pass = 0; pass < 2; pass++) {
#pragma unroll
        for (int i = 0; i < 8; i++) {
            int c = tid + i * 256;
            *(bf16x8*)(&Wt[c >> 4][(c & 15) * 8]) = wreg[i];
        }
        if (pass == 0) {
#pragma unroll
            for (int i = 0; i < 8; i++) {
                int c = tid + i * 256;
                wreg2[i] = *(const bf16x8*)(gT + (c >> 4) * 128 + (c & 15) * 8);
            }
        }
        __syncthreads();
        f32x4* acc = pass ? accT : accQ;
#pragma unroll
        for (int kk = 0; kk < 4; kk++) {
#pragma unroll
            for (int nt = 0; nt < 8; nt++) {
                bf16x8 bfr = *(const bf16x8*)(&Wt[nt * 16 + l16][kk * 32 + quad * 8]);
                acc[nt] = __builtin_amdgcn_mfma_f32_16x16x32_bf16(af[kk], bfr, acc[nt], 0, 0, 0);
            }
        }
        __syncthreads();
#pragma unroll
        for (int i = 0; i < 8; i++) wreg[i] = wreg2[i];
    }

    int cr0 = row0 + wv * 16 + quad * 4;
    int odd = l16 & 1;
    if (jp != 2) {
#pragma unroll
        for (int r = 0; r < 4; r++) {
            int cr = cr0 + r;
#pragma unroll
            for (int nt = 0; nt < 8; nt++) {
                float vQ = accQ[nt][r], vT = accT[nt][r];
                float oQ = __shfl_xor(vQ, 1);
                float oT = __shfl_xor(vT, 1);
                unsigned w;
                if (!odd) w = (unsigned)f2bf_bits(vQ) | ((unsigned)f2bf_bits(oQ) << 16);
                else      w = (unsigned)f2bf_bits(oT) | ((unsigned)f2bf_bits(vT) << 16);
                if (cr < rows) O[(size_t)cr * 128 + nt * 16 + l16] = w;
            }
        }
    } else {
#pragma unroll
        for (int r = 0; r < 4; r++) {
            int cr = cr0 + r;
            int deg = (cr < rows) ? cnt[cr] : 0;
#pragma unroll
            for (int nt = 0; nt < 8; nt++) {
                float vL = accQ[nt][r], vE = accT[nt][r];
                float oL = __shfl_xor(vL, 1);
                float oE = __shfl_xor(vE, 1);
                unsigned wl, we;
                if (!odd) {
                    wl = (unsigned)f2bf_bits(vL) | ((unsigned)f2bf_bits(oL) << 16);
                    we = (unsigned)f2bf_bits(vE) | ((unsigned)f2bf_bits(oE) << 16);
                } else {
                    wl = (unsigned)f2bf_bits(oL) | ((unsigned)f2bf_bits(vL) << 16);
                    we = (unsigned)f2bf_bits(oE) | ((unsigned)f2bf_bits(vE) << 16);
                }
                if (cr < rows && !odd)
                    loopSel[(size_t)cr * 64 + nt * 8 + (l16 >> 1)] = (deg > 0) ? wl : we;
            }
        }
    }
}

// ---- K5: wave-per-node aggregation + layernorm (R11-proven:
// wave-uniform direct broadcast loads, 8 gathers in flight per 4-edge group).
__global__ __launch_bounds__(256) void agg_kernel(
    const int* __restrict__ offs, const unsigned* __restrict__ ePack,
    const uint2* __restrict__ ST, const uint2* __restrict__ RT,
    const uint2* __restrict__ DT, const unsigned* __restrict__ loopSel,
    const void* __restrict__ normv, void* __restrict__ out,
    const int* __restrict__ flag, int N) {
    int n = blockIdx.x * 4 + threadIdx.y;
    if (n >= N) return;
    int f32 = *flag;
    int lane = threadIdx.x;
    int start = offs[n], end = offs[n + 1];
    int deg = end - start;

    unsigned ul = loopSel[(size_t)n * 64 + lane];
    uint2 ud = DT[(size_t)n * 64 + lane];
    float qd0, qd1, td0, td1, acc0, acc1;
    unpk(ud.x, qd0, qd1);
    unpk(ud.y, td0, td1);
    unpk(ul, acc0, acc1);

    float den0 = 0.f, den1 = 0.f, h0 = 0.f, h1 = 0.f;
#define GATH(PK, US, UR)                                              \
    uint2 US = ST[(size_t)((PK) & 0xFFFFFu) * 64 + lane];             \
    uint2 UR = RT[(size_t)((PK) >> 20) * 64 + lane];
#define EMATH(US, UR)                                                 \
    {                                                                 \
        float qs0, qs1, qr0, qr1, ts0, ts1, tr0, tr1;                 \
        unpk(US.x, qs0, qs1); unpk(UR.x, qr0, qr1);                   \
        unpk(US.y, ts0, ts1); unpk(UR.y, tr0, tr1);                   \
        float q0 = qs0 + qr0 + qd0, q1 = qs1 + qr1 + qd1;             \
        float a0 = q0 > 0.f ? q0 : 0.01f * q0;                        \
        float a1 = q1 > 0.f ? q1 : 0.01f * q1;                        \
        float ex0 = __expf(a0), ex1 = __expf(a1);                     \
        den0 += ex0; den1 += ex1;                                     \
        h0 += ex0 * (ts0 + tr0 + td0);                                \
        h1 += ex1 * (ts1 + tr1 + td1);                                \
    }
    int e = start;
    for (; e + 3 < end; e += 4) {
        unsigned p0 = ePack[e], p1 = ePack[e + 1], p2 = ePack[e + 2], p3 = ePack[e + 3];
        GATH(p0, sA, rA)
        GATH(p1, sB, rB)
        GATH(p2, sC, rC)
        GATH(p3, sD, rD)
        EMATH(sA, rA)
        EMATH(sB, rB)
        EMATH(sC, rC)
        EMATH(sD, rD)
    }
    for (; e < end; e++) {
        unsigned pp = ePack[e];
        GATH(pp, sE, rE)
        EMATH(sE, rE)
    }

    float x0, x1;
    if (deg > 0) {
        float nrm = ldf(normv, n, f32);
        x0 = h0 / den0 * nrm + acc0;
        x1 = h1 / den1 * nrm + acc1;
    } else {
        x0 = acc0;
        x1 = acc1;
    }

    float s = x0 + x1, ss = x0 * x0 + x1 * x1;
#pragma unroll
    for (int o = 32; o; o >>= 1) {
        s += __shfl_xor(s, o);
        ss += __shfl_xor(ss, o);
    }
    float mu = s * (1.f / 128.f);
    float var = ss * (1.f / 128.f) - mu * mu;
    float rstd = rsqrtf(var + 1e-5f);
    float y0 = (x0 - mu) * rstd, y1 = (x1 - mu) * rstd;

    if (f32) {
        ((float2*)out)[(size_t)n * 64 + lane] = make_float2(y0, y1);
    } else {
        unsigned ob = (unsigned)f2bf_bits(y0) | ((unsigned)f2bf_bits(y1) << 16);
        ((unsigned*)out)[(size_t)n * 64 + lane] = ob;
    }
}

extern "C" void kernel_launch(void* const* d_in, const int* in_sizes, int n_in,
                              void* d_out, int out_size, void* d_ws, size_t ws_size,
                              hipStream_t stream) {
    const void* node = d_in[0];
    const void* rel = d_in[1];
    const void* normv = d_in[2];
    const void* wtrip = d_in[3];
    const void* wquad = d_in[4];
    const void* loopW = d_in[5];
    const void* evoW = d_in[6];
    const int* src = (const int*)d_in[7];
    const int* dst = (const int*)d_in[8];
    const int* et = (const int*)d_in[9];

    int N = in_sizes[0] / D;
    int R = in_sizes[1] / D;
    int E = in_sizes[7];
    int nb = (N + 255) / 256;
    int nodeBlocks = (N + 63) / 64;
    int relBlocks = (R + 63) / 64;
    int scatBlocks = (E + 255) / 256;

    char* p = (char*)d_ws;
    auto alloc = [&](size_t bytes) -> void* {
        void* r = (void*)p;
        p += (bytes + 255) & ~(size_t)255;
        return r;
    };
    unsigned* nodeST = (unsigned*)alloc((size_t)N * 128 * 4);
    unsigned* nodeDT = (unsigned*)alloc((size_t)N * 128 * 4);
    unsigned* relRT = (unsigned*)alloc((size_t)R * 128 * 4);
    unsigned* loopSel = (unsigned*)alloc((size_t)N * 64 * 4);
    unsigned short* wT = (unsigned short*)alloc((size_t)8 * D * D * 2);
    int* cnt = (int*)alloc((size_t)N * 4);
    int* cur = (int*)alloc((size_t)N * 4);
    int* offs = (int*)alloc((size_t)(N + 1) * 4);
    int* part = (int*)alloc((size_t)(nb + 1) * 4);
    unsigned* ePack = (unsigned*)alloc((size_t)E * 4);
    int* flag = (int*)alloc(4);

    hipMemsetAsync(cnt, 0, (size_t)N * 4, stream);
    prep_kernel<<<272 + scatBlocks, 256, 0, stream>>>(
        node, wtrip, wquad, loopW, evoW, wT, cnt, dst, flag, E);
    scan_block<<<nb, 256, 0, stream>>>(cnt, offs, part, N);
    scan_fix<<<nb, 256, 0, stream>>>(offs, part, cur, N, E);
    int xext = nodeBlocks + (scatBlocks > relBlocks ? scatBlocks : relBlocks);
    gemm_kernel<<<dim3(xext, 3), dim3(64, 4), 0, stream>>>(
        node, rel, wT, cnt, nodeST, nodeDT, relRT, loopSel, flag, N, R, nodeBlocks,
        src, dst, et, cur, ePack, E);
    agg_kernel<<<(N + 3) / 4, dim3(64, 4), 0, stream>>>(
        offs, ePack, (const uint2*)nodeST, (const uint2*)relRT, (const uint2*)nodeDT,
        loopSel, normv, d_out, flag, N);
}

// Round 13
// 261.497 us; speedup vs baseline: 1.0886x; 1.0781x over previous
//
#include <hip/hip_runtime.h>
#include <hip/hip_bf16.h>

#define D 128
#define LOG2E 1.4426950408889634f

typedef __attribute__((ext_vector_type(8))) short bf16x8;
typedef __attribute__((ext_vector_type(4))) float f32x4;

__device__ __forceinline__ unsigned short f2bf_bits(float f) {
    union { __hip_bfloat16 h; unsigned short u; } c;
    c.h = __float2bfloat16(f);
    return c.u;
}
__device__ __forceinline__ float bfbits2f(unsigned short u) {
    return __uint_as_float(((unsigned)u) << 16);
}
__device__ __forceinline__ float ldf(const void* p, size_t i, int f32) {
    return f32 ? ((const float*)p)[i] : bfbits2f(((const unsigned short*)p)[i]);
}
__device__ __forceinline__ void unpk(unsigned u, float& a, float& b) {
    a = __uint_as_float(u << 16);
    b = __uint_as_float(u & 0xFFFF0000u);
}

// ---- K1: prep = dtype-detect (per-block local) + wq (transposed write)
//         + trans of 5 raw weights + count.
// wT job map: 0 Wsq_s 1 W_s 2 Wsq_d 3 W_d 4 loopW 5 evoW 6 Wsq_r 7 W_r
__global__ __launch_bounds__(256) void prep_kernel(
    const void* __restrict__ node, const void* __restrict__ wtrip,
    const void* __restrict__ wquad, const void* __restrict__ loopW,
    const void* __restrict__ evoW, unsigned short* __restrict__ wT,
    int* __restrict__ cnt, const int* __restrict__ dst, int* __restrict__ flag,
    int E) {
    __shared__ int sflag;
    int tid = threadIdx.x;
    int bad = 0;
    if (tid < 64) {
        for (int j = 0; j < 4; j++) {
            float v = bfbits2f(((const unsigned short*)node)[tid + 64 * j]);
            if (!(fabsf(v) < 1e4f)) bad = 1;
        }
    }
    unsigned long long m = __ballot(bad);
    if (tid == 0) sflag = (m != 0ull) ? 1 : 0;
    __syncthreads();
    int f32 = sflag;
    int bx = blockIdx.x;
    if (bx == 0 && tid == 0) *flag = f32;

    if (bx < 192) {
        int unit = bx * 2 + (tid >> 7);
        int k = unit & 127, mjob = unit >> 7;
        int t = tid & 127;
        float acc = 0.f;
        for (int j = 0; j < D; j++)
            acc += ldf(wtrip, (size_t)mjob * D * D + (size_t)k * D + j, f32) *
                   ldf(wquad, (size_t)j * D + t, f32);
        const int jmap0 = (mjob == 0) ? 0 : (mjob == 1 ? 6 : 2);
        wT[(size_t)jmap0 * D * D + (size_t)t * D + k] = f2bf_bits(acc);
    } else if (bx < 272) {
        int u = bx - 192;   // [0,80): 5 jobs x 16 segments
        int jr = u >> 4, seg = u & 15;
        const void* srcp; size_t base; int j;
        switch (jr) {
            case 0: srcp = wtrip; base = 0;             j = 1; break;
            case 1: srcp = wtrip; base = 2 * D * D;     j = 3; break;
            case 2: srcp = loopW; base = 0;             j = 4; break;
            case 3: srcp = evoW;  base = 0;             j = 5; break;
            default: srcp = wtrip; base = (size_t)D * D; j = 7; break;
        }
        for (int c = tid; c < 1024; c += 256) {
            int idx = seg * 1024 + c;
            int n = idx >> 7, k = idx & 127;
            unsigned short b = f32 ? f2bf_bits(((const float*)srcp)[base + (size_t)k * D + n])
                                   : ((const unsigned short*)srcp)[base + (size_t)k * D + n];
            wT[(size_t)j * D * D + (size_t)n * D + k] = b;
        }
    } else {
        int e = (bx - 272) * 256 + tid;
        if (e < E) atomicAdd(&cnt[dst[e]], 1);
    }
}

// ---- K2: per-block exclusive scan, block totals to part ----
__global__ void scan_block(const int* __restrict__ cnt, int* __restrict__ offs,
                           int* __restrict__ part, int N) {
    __shared__ int sh[256];
    int tid = threadIdx.x;
    int i = blockIdx.x * 256 + tid;
    int v = (i < N) ? cnt[i] : 0;
    sh[tid] = v;
    __syncthreads();
    for (int o = 1; o < 256; o <<= 1) {
        int t = (tid >= o) ? sh[tid - o] : 0;
        __syncthreads();
        sh[tid] += t;
        __syncthreads();
    }
    if (i < N) offs[i] = sh[tid] - v;
    if (tid == 255) part[blockIdx.x] = sh[255];
}

// ---- K3: each block reduces part[0..b) itself, adds carry (nb<=256) ----
__global__ void scan_fix(int* __restrict__ offs, const int* __restrict__ part,
                         int N, int E) {
    __shared__ int sh[256];
    int tid = threadIdx.x, b = blockIdx.x;
    sh[tid] = (tid < b) ? part[tid] : 0;
    __syncthreads();
    for (int o = 128; o; o >>= 1) {
        if (tid < o) sh[tid] += sh[tid + o];
        __syncthreads();
    }
    int carry = sh[0];
    int i = b * 256 + tid;
    if (i < N) offs[i] += carry;
    if (b == 0 && tid == 0) offs[N] = E;
}

// ---- K4: table GEMM (R10-proven pipeline) + scatter fused at y==1 x-overflow.
// Q (attention logit) tables pre-scaled by log2(e): exp(leaky(q)) ==
// exp2(leaky(q*log2e)) since leaky-relu commutes with positive scale.
__global__ __launch_bounds__(256) void gemm_kernel(
    const void* __restrict__ node, const void* __restrict__ rel,
    const unsigned short* __restrict__ wT, const int* __restrict__ cnt,
    unsigned* __restrict__ nodeST, unsigned* __restrict__ nodeDT,
    unsigned* __restrict__ relRT, unsigned* __restrict__ loopSel,
    const int* __restrict__ flag, int N, int R, int nodeBlocks,
    const int* __restrict__ src, const int* __restrict__ dst,
    const int* __restrict__ et, const int* __restrict__ offs,
    int* __restrict__ cur, unsigned* __restrict__ ePack, int E) {
    __shared__ __align__(16) unsigned short Wt[D][D + 8];

    int bx = blockIdx.x, by = blockIdx.y;
    int tid = threadIdx.y * 64 + threadIdx.x;
    int isRel = 0, jp;
    if (bx >= nodeBlocks) {
        if (by == 1) {  // scatter range (R10-proven form)
            int e = (bx - nodeBlocks) * 256 + tid;
            if (e < E) {
                int d = dst[e];
                int pos = offs[d] + atomicAdd(&cur[d], 1);
                ePack[pos] = (unsigned)src[e] | ((unsigned)et[e] << 20);
            }
            return;
        }
        if (by != 0 || bx - nodeBlocks >= (R + 63) / 64) return;
        isRel = 1;
        jp = 3;
    } else {
        jp = by;
    }

    int f32 = *flag;
    int rows = isRel ? R : N;
    int row0 = (isRel ? bx - nodeBlocks : bx) * 64;
    const void* A = isRel ? rel : node;

    int lane = threadIdx.x, wv = threadIdx.y;
    int l16 = lane & 15, quad = lane >> 4;
    int ar = row0 + wv * 16 + l16;
    int ar_c = ar < rows ? ar : rows - 1;

    int qIdx, tIdx;
    unsigned* O = nullptr;
    switch (jp) {
        case 0: qIdx = 0; tIdx = 1; O = nodeST; break;
        case 1: qIdx = 2; tIdx = 3; O = nodeDT; break;
        case 2: qIdx = 4; tIdx = 5; break;  // loopW/evoW pair
        default: qIdx = 6; tIdx = 7; O = relRT; break;
    }

    bf16x8 af[4];
#pragma unroll
    for (int kk = 0; kk < 4; kk++) {
        int k = kk * 32 + quad * 8;
        if (f32) {
            const float* Af = (const float*)A + (size_t)ar_c * D + k;
#pragma unroll
            for (int j = 0; j < 8; j++) af[kk][j] = (short)f2bf_bits(Af[j]);
        } else {
            af[kk] = *(const bf16x8*)((const unsigned short*)A + (size_t)ar_c * D + k);
        }
    }

    const unsigned short* gQ = wT + (size_t)qIdx * D * D;
    const unsigned short* gT = wT + (size_t)tIdx * D * D;

    bf16x8 wreg[8], wreg2[8];
#pragma unroll
    for (int i = 0; i < 8; i++) {
        int c = tid + i * 256;
        wreg[i] = *(const bf16x8*)(gQ + (c >> 4) * 128 + (c & 15) * 8);
    }

    f32x4 accQ[8], accT[8];
#pragma unroll
    for (int i = 0; i < 8; i++) {
        accQ[i] = (f32x4){0.f, 0.f, 0.f, 0.f};
        accT[i] = (f32x4){0.f, 0.f, 0.f, 0.f};
    }

    for (int pass = 0; pass < 2; pass++) {
#pragma unroll
        for (int i = 0; i < 8; i++) {
            int c = tid + i * 256;
            *(bf16x8*)(&Wt[c >> 4][(c & 15) * 8]) = wreg[i];
        }
        if (pass == 0) {
#pragma unroll
            for (int i = 0; i < 8; i++) {
                int c = tid + i * 256;
                wreg2[i] = *(const bf16x8*)(gT + (c >> 4) * 128 + (c & 15) * 8);
            }
        }
        __syncthreads();
        f32x4* acc = pass ? accT : accQ;
#pragma unroll
        for (int kk = 0; kk < 4; kk++) {
#pragma unroll
            for (int nt = 0; nt < 8; nt++) {
                bf16x8 bfr = *(const bf16x8*)(&Wt[nt * 16 + l16][kk * 32 + quad * 8]);
                acc[nt] = __builtin_amdgcn_mfma_f32_16x16x32_bf16(af[kk], bfr, acc[nt], 0, 0, 0);
            }
        }
        __syncthreads();
#pragma unroll
        for (int i = 0; i < 8; i++) wreg[i] = wreg2[i];
    }

    int cr0 = row0 + wv * 16 + quad * 4;
    int odd = l16 & 1;
    if (jp != 2) {
#pragma unroll
        for (int r = 0; r < 4; r++) {
            int cr = cr0 + r;
#pragma unroll
            for (int nt = 0; nt < 8; nt++) {
                float vQ = accQ[nt][r] * LOG2E;  // pre-scale logits for exp2
                float vT = accT[nt][r];
                float oQ = __shfl_xor(vQ, 1);
                float oT = __shfl_xor(vT, 1);
                unsigned w;
                if (!odd) w = (unsigned)f2bf_bits(vQ) | ((unsigned)f2bf_bits(oQ) << 16);
                else      w = (unsigned)f2bf_bits(oT) | ((unsigned)f2bf_bits(vT) << 16);
                if (cr < rows) O[(size_t)cr * 128 + nt * 16 + l16] = w;
            }
        }
    } else {
#pragma unroll
        for (int r = 0; r < 4; r++) {
            int cr = cr0 + r;
            int deg = (cr < rows) ? cnt[cr] : 0;
#pragma unroll
            for (int nt = 0; nt < 8; nt++) {
                float vL = accQ[nt][r], vE = accT[nt][r];
                float oL = __shfl_xor(vL, 1);
                float oE = __shfl_xor(vE, 1);
                unsigned wl, we;
                if (!odd) {
                    wl = (unsigned)f2bf_bits(vL) | ((unsigned)f2bf_bits(oL) << 16);
                    we = (unsigned)f2bf_bits(vE) | ((unsigned)f2bf_bits(oE) << 16);
                } else {
                    wl = (unsigned)f2bf_bits(oL) | ((unsigned)f2bf_bits(vL) << 16);
                    we = (unsigned)f2bf_bits(oE) | ((unsigned)f2bf_bits(vE) << 16);
                }
                if (cr < rows && !odd)
                    loopSel[(size_t)cr * 64 + nt * 8 + (l16 >> 1)] = (deg > 0) ? wl : we;
            }
        }
    }
}

// ---- K5: wave-per-node aggregation + layernorm (direct broadcast loads;
// logits pre-scaled by log2e -> bare exp2f).
__global__ __launch_bounds__(256) void agg_kernel(
    const int* __restrict__ offs, const unsigned* __restrict__ ePack,
    const uint2* __restrict__ ST, const uint2* __restrict__ RT,
    const uint2* __restrict__ DT, const unsigned* __restrict__ loopSel,
    const void* __restrict__ normv, void* __restrict__ out,
    const int* __restrict__ flag, int N) {
    int n = blockIdx.x * 4 + threadIdx.y;
    if (n >= N) return;
    int f32 = *flag;
    int lane = threadIdx.x;
    int start = offs[n], end = offs[n + 1];
    int deg = end - start;

    unsigned ul = loopSel[(size_t)n * 64 + lane];
    uint2 ud = DT[(size_t)n * 64 + lane];
    float qd0, qd1, td0, td1, acc0, acc1;
    unpk(ud.x, qd0, qd1);
    unpk(ud.y, td0, td1);
    unpk(ul, acc0, acc1);

    float den0 = 0.f, den1 = 0.f, h0 = 0.f, h1 = 0.f;
#define GATH(PK, US, UR)                                              \
    uint2 US = ST[(size_t)((PK) & 0xFFFFFu) * 64 + lane];             \
    uint2 UR = RT[(size_t)((PK) >> 20) * 64 + lane];
#define EMATH(US, UR)                                                 \
    {                                                                 \
        float qs0, qs1, qr0, qr1, ts0, ts1, tr0, tr1;                 \
        unpk(US.x, qs0, qs1); unpk(UR.x, qr0, qr1);                   \
        unpk(US.y, ts0, ts1); unpk(UR.y, tr0, tr1);                   \
        float q0 = qs0 + qr0 + qd0, q1 = qs1 + qr1 + qd1;             \
        float a0 = q0 > 0.f ? q0 : 0.01f * q0;                        \
        float a1 = q1 > 0.f ? q1 : 0.01f * q1;                        \
        float ex0 = exp2f(a0), ex1 = exp2f(a1);                       \
        den0 += ex0; den1 += ex1;                                     \
        h0 += ex0 * (ts0 + tr0 + td0);                                \
        h1 += ex1 * (ts1 + tr1 + td1);                                \
    }
    int e = start;
    for (; e + 3 < end; e += 4) {
        unsigned p0 = ePack[e], p1 = ePack[e + 1], p2 = ePack[e + 2], p3 = ePack[e + 3];
        GATH(p0, sA, rA)
        GATH(p1, sB, rB)
        GATH(p2, sC, rC)
        GATH(p3, sD, rD)
        EMATH(sA, rA)
        EMATH(sB, rB)
        EMATH(sC, rC)
        EMATH(sD, rD)
    }
    for (; e < end; e++) {
        unsigned pp = ePack[e];
        GATH(pp, sE, rE)
        EMATH(sE, rE)
    }

    float x0, x1;
    if (deg > 0) {
        float nrm = ldf(normv, n, f32);
        x0 = h0 / den0 * nrm + acc0;
        x1 = h1 / den1 * nrm + acc1;
    } else {
        x0 = acc0;
        x1 = acc1;
    }

    float s = x0 + x1, ss = x0 * x0 + x1 * x1;
#pragma unroll
    for (int o = 32; o; o >>= 1) {
        s += __shfl_xor(s, o);
        ss += __shfl_xor(ss, o);
    }
    float mu = s * (1.f / 128.f);
    float var = ss * (1.f / 128.f) - mu * mu;
    float rstd = rsqrtf(var + 1e-5f);
    float y0 = (x0 - mu) * rstd, y1 = (x1 - mu) * rstd;

    if (f32) {
        ((float2*)out)[(size_t)n * 64 + lane] = make_float2(y0, y1);
    } else {
        unsigned ob = (unsigned)f2bf_bits(y0) | ((unsigned)f2bf_bits(y1) << 16);
        ((unsigned*)out)[(size_t)n * 64 + lane] = ob;
    }
}

extern "C" void kernel_launch(void* const* d_in, const int* in_sizes, int n_in,
                              void* d_out, int out_size, void* d_ws, size_t ws_size,
                              hipStream_t stream) {
    const void* node = d_in[0];
    const void* rel = d_in[1];
    const void* normv = d_in[2];
    const void* wtrip = d_in[3];
    const void* wquad = d_in[4];
    const void* loopW = d_in[5];
    const void* evoW = d_in[6];
    const int* src = (const int*)d_in[7];
    const int* dst = (const int*)d_in[8];
    const int* et = (const int*)d_in[9];

    int N = in_sizes[0] / D;
    int R = in_sizes[1] / D;
    int E = in_sizes[7];
    int nb = (N + 255) / 256;
    int nodeBlocks = (N + 63) / 64;
    int relBlocks = (R + 63) / 64;
    int scatBlocks = (E + 255) / 256;

    char* p = (char*)d_ws;
    auto alloc = [&](size_t bytes) -> void* {
        void* r = (void*)p;
        p += (bytes + 255) & ~(size_t)255;
        return r;
    };
    unsigned* nodeST = (unsigned*)alloc((size_t)N * 128 * 4);
    unsigned* nodeDT = (unsigned*)alloc((size_t)N * 128 * 4);
    unsigned* relRT = (unsigned*)alloc((size_t)R * 128 * 4);
    unsigned* loopSel = (unsigned*)alloc((size_t)N * 64 * 4);
    unsigned short* wT = (unsigned short*)alloc((size_t)8 * D * D * 2);
    int* cnt = (int*)alloc((size_t)2 * N * 4);  // cnt | cur
    int* offs = (int*)alloc((size_t)(N + 1) * 4);
    int* part = (int*)alloc((size_t)(nb + 1) * 4);
    unsigned* ePack = (unsigned*)alloc((size_t)E * 4);
    int* flag = (int*)alloc(4);

    hipMemsetAsync(cnt, 0, (size_t)2 * N * 4, stream);
    prep_kernel<<<272 + scatBlocks, 256, 0, stream>>>(
        node, wtrip, wquad, loopW, evoW, wT, cnt, dst, flag, E);
    scan_block<<<nb, 256, 0, stream>>>(cnt, offs, part, N);
    scan_fix<<<nb, 256, 0, stream>>>(offs, part, N, E);
    int xext = nodeBlocks + (scatBlocks > relBlocks ? scatBlocks : relBlocks);
    gemm_kernel<<<dim3(xext, 3), dim3(64, 4), 0, stream>>>(
        node, rel, wT, cnt, nodeST, nodeDT, relRT, loopSel, flag, N, R, nodeBlocks,
        src, dst, et, offs, cnt + N, ePack, E);
    agg_kernel<<<(N + 3) / 4, dim3(64, 4), 0, stream>>>(
        offs, ePack, (const uint2*)nodeST, (const uint2*)relRT, (const uint2*)nodeDT,
        loopSel, normv, d_out, flag, N);
}

// Round 14
// 236.064 us; speedup vs baseline: 1.2059x; 1.1077x over previous
//
#include <hip/hip_runtime.h>
#include <hip/hip_bf16.h>

#define D 128
#define LOG2E 1.4426950408889634f

typedef __attribute__((ext_vector_type(8))) short bf16x8;
typedef __attribute__((ext_vector_type(4))) float f32x4;

__device__ __forceinline__ unsigned short f2bf_bits(float f) {
    union { __hip_bfloat16 h; unsigned short u; } c;
    c.h = __float2bfloat16(f);
    return c.u;
}
__device__ __forceinline__ float bfbits2f(unsigned short u) {
    return __uint_as_float(((unsigned)u) << 16);
}
__device__ __forceinline__ float ldf(const void* p, size_t i, int f32) {
    return f32 ? ((const float*)p)[i] : bfbits2f(((const unsigned short*)p)[i]);
}
__device__ __forceinline__ void unpk(unsigned u, float& a, float& b) {
    a = __uint_as_float(u << 16);
    b = __uint_as_float(u & 0xFFFF0000u);
}

// ---- K1: prep = dtype-detect (per-block local) + wq (transposed write)
//         + trans of 5 raw weights + count (rank captured for free).
// wT job map: 0 Wsq_s 1 W_s 2 Wsq_d 3 W_d 4 loopW 5 evoW 6 Wsq_r 7 W_r
__global__ __launch_bounds__(256) void prep_kernel(
    const void* __restrict__ node, const void* __restrict__ wtrip,
    const void* __restrict__ wquad, const void* __restrict__ loopW,
    const void* __restrict__ evoW, unsigned short* __restrict__ wT,
    int* __restrict__ cnt, int* __restrict__ rank,
    const int* __restrict__ dst, int* __restrict__ flag, int E) {
    __shared__ int sflag;
    int tid = threadIdx.x;
    int bad = 0;
    if (tid < 64) {
        for (int j = 0; j < 4; j++) {
            float v = bfbits2f(((const unsigned short*)node)[tid + 64 * j]);
            if (!(fabsf(v) < 1e4f)) bad = 1;
        }
    }
    unsigned long long m = __ballot(bad);
    if (tid == 0) sflag = (m != 0ull) ? 1 : 0;
    __syncthreads();
    int f32 = sflag;
    int bx = blockIdx.x;
    if (bx == 0 && tid == 0) *flag = f32;

    if (bx < 192) {
        int unit = bx * 2 + (tid >> 7);
        int k = unit & 127, mjob = unit >> 7;
        int t = tid & 127;
        float acc = 0.f;
        for (int j = 0; j < D; j++)
            acc += ldf(wtrip, (size_t)mjob * D * D + (size_t)k * D + j, f32) *
                   ldf(wquad, (size_t)j * D + t, f32);
        const int jmap0 = (mjob == 0) ? 0 : (mjob == 1 ? 6 : 2);
        wT[(size_t)jmap0 * D * D + (size_t)t * D + k] = f2bf_bits(acc);
    } else if (bx < 272) {
        int u = bx - 192;   // [0,80): 5 jobs x 16 segments
        int jr = u >> 4, seg = u & 15;
        const void* srcp; size_t base; int j;
        switch (jr) {
            case 0: srcp = wtrip; base = 0;             j = 1; break;
            case 1: srcp = wtrip; base = 2 * D * D;     j = 3; break;
            case 2: srcp = loopW; base = 0;             j = 4; break;
            case 3: srcp = evoW;  base = 0;             j = 5; break;
            default: srcp = wtrip; base = (size_t)D * D; j = 7; break;
        }
        for (int c = tid; c < 1024; c += 256) {
            int idx = seg * 1024 + c;
            int n = idx >> 7, k = idx & 127;
            unsigned short b = f32 ? f2bf_bits(((const float*)srcp)[base + (size_t)k * D + n])
                                   : ((const unsigned short*)srcp)[base + (size_t)k * D + n];
            wT[(size_t)j * D * D + (size_t)n * D + k] = b;
        }
    } else {
        int e = (bx - 272) * 256 + tid;
        if (e < E) rank[e] = atomicAdd(&cnt[dst[e]], 1);
    }
}

// ---- K2: per-block exclusive scan, block totals to part ----
__global__ void scan_block(const int* __restrict__ cnt, int* __restrict__ offs,
                           int* __restrict__ part, int N) {
    __shared__ int sh[256];
    int tid = threadIdx.x;
    int i = blockIdx.x * 256 + tid;
    int v = (i < N) ? cnt[i] : 0;
    sh[tid] = v;
    __syncthreads();
    for (int o = 1; o < 256; o <<= 1) {
        int t = (tid >= o) ? sh[tid - o] : 0;
        __syncthreads();
        sh[tid] += t;
        __syncthreads();
    }
    if (i < N) offs[i] = sh[tid] - v;
    if (tid == 255) part[blockIdx.x] = sh[255];
}

// ---- K3: each block reduces part[0..b) itself, adds carry (nb<=256) ----
__global__ void scan_fix(int* __restrict__ offs, const int* __restrict__ part,
                         int N, int E) {
    __shared__ int sh[256];
    int tid = threadIdx.x, b = blockIdx.x;
    sh[tid] = (tid < b) ? part[tid] : 0;
    __syncthreads();
    for (int o = 128; o; o >>= 1) {
        if (tid < o) sh[tid] += sh[tid + o];
        __syncthreads();
    }
    int carry = sh[0];
    int i = b * 256 + tid;
    if (i < N) offs[i] += carry;
    if (b == 0 && tid == 0) offs[N] = E;
}

// ---- K4: table GEMM, 512-thread blocks (8 waves, 128 rows): same 2-pass
// register-prefetch pipeline, doubled LDS reuse and residency. Scatter fused
// at y==1 x-overflow, atomic-free via precomputed rank.
__global__ __launch_bounds__(512) void gemm_kernel(
    const void* __restrict__ node, const void* __restrict__ rel,
    const unsigned short* __restrict__ wT, const int* __restrict__ cnt,
    unsigned* __restrict__ nodeST, unsigned* __restrict__ nodeDT,
    unsigned* __restrict__ relRT, unsigned* __restrict__ loopSel,
    const int* __restrict__ flag, int N, int R, int nodeBlocks,
    const int* __restrict__ src, const int* __restrict__ dst,
    const int* __restrict__ et, const int* __restrict__ offs,
    const int* __restrict__ rank, unsigned* __restrict__ ePack, int E) {
    __shared__ __align__(16) unsigned short Wt[D][D + 8];

    int bx = blockIdx.x, by = blockIdx.y;
    int tid = threadIdx.y * 64 + threadIdx.x;
    int isRel = 0, jp;
    if (bx >= nodeBlocks) {
        if (by == 1) {  // scatter range: pure (no atomics)
            int e = (bx - nodeBlocks) * 512 + tid;
            if (e < E) {
                int d = dst[e];
                ePack[offs[d] + rank[e]] = (unsigned)src[e] | ((unsigned)et[e] << 20);
            }
            return;
        }
        if (by != 0 || bx - nodeBlocks >= (R + 127) / 128) return;
        isRel = 1;
        jp = 3;
    } else {
        jp = by;
    }

    int f32 = *flag;
    int rows = isRel ? R : N;
    int row0 = (isRel ? bx - nodeBlocks : bx) * 128;
    const void* A = isRel ? rel : node;

    int lane = threadIdx.x, wv = threadIdx.y;  // wv in [0,8)
    int l16 = lane & 15, quad = lane >> 4;
    int ar = row0 + wv * 16 + l16;
    int ar_c = ar < rows ? ar : rows - 1;

    int qIdx, tIdx;
    unsigned* O = nullptr;
    switch (jp) {
        case 0: qIdx = 0; tIdx = 1; O = nodeST; break;
        case 1: qIdx = 2; tIdx = 3; O = nodeDT; break;
        case 2: qIdx = 4; tIdx = 5; break;  // loopW/evoW pair
        default: qIdx = 6; tIdx = 7; O = relRT; break;
    }

    bf16x8 af[4];
#pragma unroll
    for (int kk = 0; kk < 4; kk++) {
        int k = kk * 32 + quad * 8;
        if (f32) {
            const float* Af = (const float*)A + (size_t)ar_c * D + k;
#pragma unroll
            for (int j = 0; j < 8; j++) af[kk][j] = (short)f2bf_bits(Af[j]);
        } else {
            af[kk] = *(const bf16x8*)((const unsigned short*)A + (size_t)ar_c * D + k);
        }
    }

    const unsigned short* gQ = wT + (size_t)qIdx * D * D;
    const unsigned short* gT = wT + (size_t)tIdx * D * D;

    bf16x8 wreg[4], wreg2[4];
#pragma unroll
    for (int i = 0; i < 4; i++) {
        int c = tid + i * 512;
        wreg[i] = *(const bf16x8*)(gQ + (c >> 4) * 128 + (c & 15) * 8);
    }

    f32x4 accQ[8], accT[8];
#pragma unroll
    for (int i = 0; i < 8; i++) {
        accQ[i] = (f32x4){0.f, 0.f, 0.f, 0.f};
        accT[i] = (f32x4){0.f, 0.f, 0.f, 0.f};
    }

    for (int pass = 0; pass < 2; pass++) {
#pragma unroll
        for (int i = 0; i < 4; i++) {
            int c = tid + i * 512;
            *(bf16x8*)(&Wt[c >> 4][(c & 15) * 8]) = wreg[i];
        }
        if (pass == 0) {
#pragma unroll
            for (int i = 0; i < 4; i++) {
                int c = tid + i * 512;
                wreg2[i] = *(const bf16x8*)(gT + (c >> 4) * 128 + (c & 15) * 8);
            }
        }
        __syncthreads();
        f32x4* acc = pass ? accT : accQ;
#pragma unroll
        for (int kk = 0; kk < 4; kk++) {
#pragma unroll
            for (int nt = 0; nt < 8; nt++) {
                bf16x8 bfr = *(const bf16x8*)(&Wt[nt * 16 + l16][kk * 32 + quad * 8]);
                acc[nt] = __builtin_amdgcn_mfma_f32_16x16x32_bf16(af[kk], bfr, acc[nt], 0, 0, 0);
            }
        }
        __syncthreads();
#pragma unroll
        for (int i = 0; i < 4; i++) wreg[i] = wreg2[i];
    }

    int cr0 = row0 + wv * 16 + quad * 4;
    int odd = l16 & 1;
    if (jp != 2) {
#pragma unroll
        for (int r = 0; r < 4; r++) {
            int cr = cr0 + r;
#pragma unroll
            for (int nt = 0; nt < 8; nt++) {
                float vQ = accQ[nt][r] * LOG2E;  // pre-scale logits for exp2
                float vT = accT[nt][r];
                float oQ = __shfl_xor(vQ, 1);
                float oT = __shfl_xor(vT, 1);
                unsigned w;
                if (!odd) w = (unsigned)f2bf_bits(vQ) | ((unsigned)f2bf_bits(oQ) << 16);
                else      w = (unsigned)f2bf_bits(oT) | ((unsigned)f2bf_bits(vT) << 16);
                if (cr < rows) O[(size_t)cr * 128 + nt * 16 + l16] = w;
            }
        }
    } else {
#pragma unroll
        for (int r = 0; r < 4; r++) {
            int cr = cr0 + r;
            int deg = (cr < rows) ? cnt[cr] : 0;
#pragma unroll
            for (int nt = 0; nt < 8; nt++) {
                float vL = accQ[nt][r], vE = accT[nt][r];
                float oL = __shfl_xor(vL, 1);
                float oE = __shfl_xor(vE, 1);
                unsigned wl, we;
                if (!odd) {
                    wl = (unsigned)f2bf_bits(vL) | ((unsigned)f2bf_bits(oL) << 16);
                    we = (unsigned)f2bf_bits(vE) | ((unsigned)f2bf_bits(oE) << 16);
                } else {
                    wl = (unsigned)f2bf_bits(oL) | ((unsigned)f2bf_bits(vL) << 16);
                    we = (unsigned)f2bf_bits(oE) | ((unsigned)f2bf_bits(vE) << 16);
                }
                if (cr < rows && !odd)
                    loopSel[(size_t)cr * 64 + nt * 8 + (l16 >> 1)] = (deg > 0) ? wl : we;
            }
        }
    }
}

// ---- K5: wave-per-node aggregation + layernorm (direct broadcast loads;
// logits pre-scaled by log2e -> bare exp2f).
__global__ __launch_bounds__(256) void agg_kernel(
    const int* __restrict__ offs, const unsigned* __restrict__ ePack,
    const uint2* __restrict__ ST, const uint2* __restrict__ RT,
    const uint2* __restrict__ DT, const unsigned* __restrict__ loopSel,
    const void* __restrict__ normv, void* __restrict__ out,
    const int* __restrict__ flag, int N) {
    int n = blockIdx.x * 4 + threadIdx.y;
    if (n >= N) return;
    int f32 = *flag;
    int lane = threadIdx.x;
    int start = offs[n], end = offs[n + 1];
    int deg = end - start;

    unsigned ul = loopSel[(size_t)n * 64 + lane];
    uint2 ud = DT[(size_t)n * 64 + lane];
    float qd0, qd1, td0, td1, acc0, acc1;
    unpk(ud.x, qd0, qd1);
    unpk(ud.y, td0, td1);
    unpk(ul, acc0, acc1);

    float den0 = 0.f, den1 = 0.f, h0 = 0.f, h1 = 0.f;
#define GATH(PK, US, UR)                                              \
    uint2 US = ST[(size_t)((PK) & 0xFFFFFu) * 64 + lane];             \
    uint2 UR = RT[(size_t)((PK) >> 20) * 64 + lane];
#define EMATH(US, UR)                                                 \
    {                                                                 \
        float qs0, qs1, qr0, qr1, ts0, ts1, tr0, tr1;                 \
        unpk(US.x, qs0, qs1); unpk(UR.x, qr0, qr1);                   \
        unpk(US.y, ts0, ts1); unpk(UR.y, tr0, tr1);                   \
        float q0 = qs0 + qr0 + qd0, q1 = qs1 + qr1 + qd1;             \
        float a0 = q0 > 0.f ? q0 : 0.01f * q0;                        \
        float a1 = q1 > 0.f ? q1 : 0.01f * q1;                        \
        float ex0 = exp2f(a0), ex1 = exp2f(a1);                       \
        den0 += ex0; den1 += ex1;                                     \
        h0 += ex0 * (ts0 + tr0 + td0);                                \
        h1 += ex1 * (ts1 + tr1 + td1);                                \
    }
    int e = start;
    for (; e + 3 < end; e += 4) {
        unsigned p0 = ePack[e], p1 = ePack[e + 1], p2 = ePack[e + 2], p3 = ePack[e + 3];
        GATH(p0, sA, rA)
        GATH(p1, sB, rB)
        GATH(p2, sC, rC)
        GATH(p3, sD, rD)
        EMATH(sA, rA)
        EMATH(sB, rB)
        EMATH(sC, rC)
        EMATH(sD, rD)
    }
    for (; e < end; e++) {
        unsigned pp = ePack[e];
        GATH(pp, sE, rE)
        EMATH(sE, rE)
    }

    float x0, x1;
    if (deg > 0) {
        float nrm = ldf(normv, n, f32);
        x0 = h0 / den0 * nrm + acc0;
        x1 = h1 / den1 * nrm + acc1;
    } else {
        x0 = acc0;
        x1 = acc1;
    }

    float s = x0 + x1, ss = x0 * x0 + x1 * x1;
#pragma unroll
    for (int o = 32; o; o >>= 1) {
        s += __shfl_xor(s, o);
        ss += __shfl_xor(ss, o);
    }
    float mu = s * (1.f / 128.f);
    float var = ss * (1.f / 128.f) - mu * mu;
    float rstd = rsqrtf(var + 1e-5f);
    float y0 = (x0 - mu) * rstd, y1 = (x1 - mu) * rstd;

    if (f32) {
        ((float2*)out)[(size_t)n * 64 + lane] = make_float2(y0, y1);
    } else {
        unsigned ob = (unsigned)f2bf_bits(y0) | ((unsigned)f2bf_bits(y1) << 16);
        ((unsigned*)out)[(size_t)n * 64 + lane] = ob;
    }
}

extern "C" void kernel_launch(void* const* d_in, const int* in_sizes, int n_in,
                              void* d_out, int out_size, void* d_ws, size_t ws_size,
                              hipStream_t stream) {
    const void* node = d_in[0];
    const void* rel = d_in[1];
    const void* normv = d_in[2];
    const void* wtrip = d_in[3];
    const void* wquad = d_in[4];
    const void* loopW = d_in[5];
    const void* evoW = d_in[6];
    const int* src = (const int*)d_in[7];
    const int* dst = (const int*)d_in[8];
    const int* et = (const int*)d_in[9];

    int N = in_sizes[0] / D;
    int R = in_sizes[1] / D;
    int E = in_sizes[7];
    int nb = (N + 255) / 256;
    int nodeBlocks = (N + 127) / 128;
    int relBlocks = (R + 127) / 128;
    int scatBlocks = (E + 511) / 512;

    char* p = (char*)d_ws;
    auto alloc = [&](size_t bytes) -> void* {
        void* r = (void*)p;
        p += (bytes + 255) & ~(size_t)255;
        return r;
    };
    unsigned* nodeST = (unsigned*)alloc((size_t)N * 128 * 4);
    unsigned* nodeDT = (unsigned*)alloc((size_t)N * 128 * 4);
    unsigned* relRT = (unsigned*)alloc((size_t)R * 128 * 4);
    unsigned* loopSel = (unsigned*)alloc((size_t)N * 64 * 4);
    unsigned short* wT = (unsigned short*)alloc((size_t)8 * D * D * 2);
    int* cnt = (int*)alloc((size_t)N * 4);
    int* offs = (int*)alloc((size_t)(N + 1) * 4);
    int* part = (int*)alloc((size_t)(nb + 1) * 4);
    int* rank = (int*)alloc((size_t)E * 4);
    unsigned* ePack = (unsigned*)alloc((size_t)E * 4);
    int* flag = (int*)alloc(4);

    hipMemsetAsync(cnt, 0, (size_t)N * 4, stream);
    prep_kernel<<<272 + (E + 255) / 256, 256, 0, stream>>>(
        node, wtrip, wquad, loopW, evoW, wT, cnt, rank, dst, flag, E);
    scan_block<<<nb, 256, 0, stream>>>(cnt, offs, part, N);
    scan_fix<<<nb, 256, 0, stream>>>(offs, part, N, E);
    int xext = nodeBlocks + (scatBlocks > relBlocks ? scatBlocks : relBlocks);
    gemm_kernel<<<dim3(xext, 3), dim3(64, 8), 0, stream>>>(
        node, rel, wT, cnt, nodeST, nodeDT, relRT, loopSel, flag, N, R, nodeBlocks,
        src, dst, et, offs, rank, ePack, E);
    agg_kernel<<<(N + 3) / 4, dim3(64, 4), 0, stream>>>(
        offs, ePack, (const uint2*)nodeST, (const uint2*)relRT, (const uint2*)nodeDT,
        loopSel, normv, d_out, flag, N);
}